// Round 3
// baseline (4332.697 us; speedup 1.0000x reference)
//
#include <hip/hip_runtime.h>

constexpr int D    = 16;
constexpr int KOPS = 5;
constexpr int LAYERS = 25;
constexpr int SAMPLES_PER_BLOCK = 16;
constexpr int THREADS = SAMPLES_PER_BLOCK * D;   // 256
constexpr int B_TOTAL = 16384;

// U word layout: s*520 + (i*16 + l)*2 + {re,im}; 520 keeps float4 16B-aligned
// and staggers samples across banks (8-bank offset per sample).
constexpr int U_STRIDE = 520;

__global__ __launch_bounds__(THREADS, 3)
void hqmm_kernel(const float* __restrict__ sr, const float* __restrict__ si,
                 const float* __restrict__ kr, const float* __restrict__ ki,
                 float* __restrict__ out)
{
    __shared__ float2 AT[KOPS][D][D];          // AT[k][l][m] = A[k][m][l], 10 KB
    __shared__ float  U[SAMPLES_PER_BLOCK * U_STRIDE];   // 33.3 KB

    const int tid = threadIdx.x;
    const int s   = tid >> 4;        // local sample 0..15 (0..3 within a wave)
    const int c   = tid & 15;        // owned column
    const long b  = (long)blockIdx.x * SAMPLES_PER_BLOCK + s;

    // load rho column c into registers
    float rr[D], ri[D];
    const float* srb = sr + b * (D * D);
    const float* sib = si + b * (D * D);
#pragma unroll
    for (int j = 0; j < D; ++j) {
        rr[j] = srb[j * D + c];
        ri[j] = sib[j * D + c];
    }

#pragma unroll 1
    for (int layer = 0; layer < LAYERS; ++layer) {
        const float* krl = kr + (size_t)layer * KOPS * D * D;
        const float* kil = ki + (size_t)layer * KOPS * D * D;

        // stage conj-transpose source: AT[k][l][m] = A[k][m][l]
        for (int idx = tid; idx < KOPS * D * D; idx += THREADS) {
            int k   = idx >> 8;
            int rem = idx & 255;
            int l   = rem >> 4;
            int m   = rem & 15;
            AT[k][l][m] = make_float2(krl[(k * D + m) * D + l],
                                      kil[(k * D + m) * D + l]);
        }
        // visibility of AT guaranteed by the sync after the U writes below

        float accr[D], acci[D];
#pragma unroll
        for (int i = 0; i < D; ++i) { accr[i] = 0.f; acci[i] = 0.f; }

#pragma unroll 1
        for (int k = 0; k < KOPS; ++k) {
            // ---- phase 1 (thread-local): U[:,c] = A_k @ rho[:,c]
            // A read with block-uniform addresses -> scalar loads (s_load),
            // broadcast for free, no LDS traffic.
            const float* ka = krl + k * D * D;
            const float* kb = kil + k * D * D;
            float ur[D], ui[D];
#pragma unroll
            for (int i = 0; i < D; ++i) {
                float xr = 0.f, xi = 0.f;
#pragma unroll
                for (int j = 0; j < D; ++j) {
                    float ar = ka[i * D + j];
                    float ai = kb[i * D + j];
                    xr += ar * rr[j] - ai * ri[j];
                    xi += ar * ri[j] + ai * rr[j];
                }
                ur[i] = xr; ui[i] = xi;
            }
            // publish U column
#pragma unroll
            for (int i = 0; i < D; ++i) {
                int w = s * U_STRIDE + (i * D + c) * 2;
                U[w]     = ur[i];
                U[w + 1] = ui[i];
            }
            __syncthreads();

            // ---- phase 2: acc[:,c] += sum_l U[:,l] * conj(A_k[c,l])
#pragma unroll
            for (int lp = 0; lp < D / 2; ++lp) {
                float2 a0 = AT[k][2 * lp][c];
                float2 a1 = AT[k][2 * lp + 1][c];
#pragma unroll
                for (int i = 0; i < D; ++i) {
                    const float4 u = *reinterpret_cast<const float4*>(
                        &U[s * U_STRIDE + (i * D + 2 * lp) * 2]);
                    accr[i] += u.x * a0.x + u.y * a0.y;
                    acci[i] += u.y * a0.x - u.x * a0.y;
                    accr[i] += u.z * a1.x + u.w * a1.y;
                    acci[i] += u.w * a1.x - u.z * a1.y;
                }
            }
            __syncthreads();   // protect U (and AT on last k) before reuse
        }

#pragma unroll
        for (int i = 0; i < D; ++i) { rr[i] = accr[i]; ri[i] = acci[i]; }
    }

    // out is [B,D,D,2]; write (re,im) pairs as float2 -> coalesced
    float2* o2 = reinterpret_cast<float2*>(out);
#pragma unroll
    for (int i = 0; i < D; ++i) {
        o2[(b * D + i) * D + c] = make_float2(rr[i], ri[i]);
    }
}

extern "C" void kernel_launch(void* const* d_in, const int* in_sizes, int n_in,
                              void* d_out, int out_size, void* d_ws, size_t ws_size,
                              hipStream_t stream) {
    const float* sr = (const float*)d_in[0];
    const float* si = (const float*)d_in[1];
    const float* kr = (const float*)d_in[2];
    const float* ki = (const float*)d_in[3];
    float* out = (float*)d_out;

    dim3 grid(B_TOTAL / SAMPLES_PER_BLOCK);
    hqmm_kernel<<<grid, THREADS, 0, stream>>>(sr, si, kr, ki, out);
}

// Round 7
// 1666.035 us; speedup vs baseline: 2.6006x; 2.6006x over previous
//
#include <hip/hip_runtime.h>

constexpr int KOPS   = 5;
constexpr int LAYERS = 25;
constexpr int B_TOTAL = 16384;

typedef unsigned int u32;
using f32x4 = __attribute__((ext_vector_type(4))) float;
using s16x8 = __attribute__((ext_vector_type(8))) short;

// ---------------- shared helpers ----------------
// Round-to-nearest bf16 top-16-bits of a f32 bit pattern.
__device__ __forceinline__ u32 rtn16(u32 u) {
  return u + 0x7FFFu + ((u >> 16) & 1u);
}
// 3-level RTN bf16 split: x ~= h + m + l with residual exactness (Sterbenz),
// representation error ~2^-24 relative — fp32-grade per layer.
__device__ __forceinline__ void split3f(float x, u32& h, u32& m, u32& l) {
  u32 u0 = __float_as_uint(x);
  u32 hb = rtn16(u0) & 0xFFFF0000u;
  float r1 = x - __uint_as_float(hb);
  u32 u1 = __float_as_uint(r1);
  u32 mb = rtn16(u1) & 0xFFFF0000u;
  float r2 = r1 - __uint_as_float(mb);
  u32 u2 = __float_as_uint(r2);
  h = hb >> 16; m = mb >> 16; l = rtn16(u2) >> 16;
}

// ---------------- MFMA path constants ----------------
constexpr int NT = 32;             // samples per block
constexpr int MF_THREADS = 512;    // 8 waves
// One (layer,c8,part) chunk: 3 splits * 256 rows * 32 cols * 2B, pre-swizzled.
constexpr u32 W_CHUNK = 49152;
constexpr size_t W_TOTAL = (size_t)LAYERS * 8 * 2 * W_CHUNK;  // 19,660,800 B

__device__ __forceinline__ void gload_lds16(const void* g, void* l) {
  __builtin_amdgcn_global_load_lds(
      (const __attribute__((address_space(1))) void*)g,
      (__attribute__((address_space(3))) void*)l, 16, 0, 0);
}

// ---------------- W precompute ----------------
// W[r=i*16+m][c=j*16+l] = sum_k A_k[i][j] * conj(A_k[m][l])
// Stored as bf16 3-splits, row-major [su][row][32 cols] per (layer,c8,part),
// byte-addresses XOR-swizzled with ((row&7)<<4) == the LDS read swizzle.
__global__ __launch_bounds__(256)
void build_w(const float* __restrict__ kr, const float* __restrict__ ki,
             char* __restrict__ ws)
{
  const int layer = blockIdx.x >> 3;
  const int c8    = blockIdx.x & 7;
  const int r     = threadIdx.x;
  __shared__ float Ar[KOPS*256];
  __shared__ float Ai[KOPS*256];
  for (int t = r; t < KOPS*256; t += 256) {
    Ar[t] = kr[layer*KOPS*256 + t];
    Ai[t] = ki[layer*KOPS*256 + t];
  }
  __syncthreads();
  const int i = r >> 4, m = r & 15;
  char* base = ws + (size_t)((layer*8 + c8)*2) * W_CHUNK;
  const u32 swz = (u32)((r & 7) << 4);
  for (int cc = 0; cc < 32; ++cc) {
    const int c = c8*32 + cc;
    const int j = c >> 4, l = c & 15;
    float wr = 0.f, wi = 0.f;
    for (int k = 0; k < KOPS; ++k) {
      float ar = Ar[k*256 + i*16 + j], ai = Ai[k*256 + i*16 + j];
      float br = Ar[k*256 + m*16 + l], bi = Ai[k*256 + m*16 + l];
      wr += ar*br + ai*bi;          // re(A * conj(B))
      wi += ai*br - ar*bi;          // im(A * conj(B))
    }
    u32 s0,s1,s2, t0,t1,t2;
    split3f(wr, s0,s1,s2);
    split3f(wi, t0,t1,t2);
    const u32 lin0 = (u32)((0*256 + r)*64 + cc*2);
    const u32 lin1 = (u32)((1*256 + r)*64 + cc*2);
    const u32 lin2 = (u32)((2*256 + r)*64 + cc*2);
    *(unsigned short*)(base + (lin0 ^ swz)) = (unsigned short)s0;
    *(unsigned short*)(base + (lin1 ^ swz)) = (unsigned short)s1;
    *(unsigned short*)(base + (lin2 ^ swz)) = (unsigned short)s2;
    *(unsigned short*)(base + W_CHUNK + (lin0 ^ swz)) = (unsigned short)t0;
    *(unsigned short*)(base + W_CHUNK + (lin1 ^ swz)) = (unsigned short)t1;
    *(unsigned short*)(base + W_CHUNK + (lin2 ^ swz)) = (unsigned short)t2;
  }
}

// ---------------- main MFMA kernel ----------------
// Per block: 32 samples through all 25 layers.
// State S: 3 splits x [32 samples][512 = re256|im256] bf16, XOR-swizzled,
// updated in place per layer. W staged per (c8, part) chunk (49 KB).
// Per c8: Cr += Wr*Xr - Wi*Xi ; Ci += Wi*Xr + Wr*Xi over 8 split-term pairs.
__global__ __launch_bounds__(MF_THREADS, 2)
void hqmm_mfma(const float* __restrict__ sr, const float* __restrict__ si,
               const char* __restrict__ ws, float* __restrict__ out)
{
  __shared__ char smem[147456];
  char* Sbuf = smem;                 // 98304 B
  char* Wbuf = smem + 98304;         // 49152 B

  const int tid  = threadIdx.x;
  const int lane = tid & 63;
  const int wv   = tid >> 6;         // wave 0..7 -> M rows [wv*32, wv*32+32)
  const int nloc = lane & 15;
  const int g    = lane >> 4;        // k-group of the MFMA fragment
  const long sample_base = (long)blockIdx.x * NT;
  const u32 swz = (u32)((lane & 7) << 4);
  const int m0 = wv * 32;

  // ---- init: load fp32 state, split, store to Sbuf ----
  for (int t = tid; t < NT*256; t += MF_THREADS) {
    const int n = t >> 8;
    const int e = t & 255;
    const float xr = sr[(sample_base + n)*256 + e];
    const float xi = si[(sample_base + n)*256 + e];
    u32 a0,a1,a2, b0,b1,b2;
    split3f(xr, a0,a1,a2);
    split3f(xi, b0,b1,b2);
    const u32 sw = (u32)((n & 7) << 4);
    const u32 nb = (u32)(n * 1024);
    *(unsigned short*)(Sbuf + ((0*32768 + nb + e*2      ) ^ sw)) = (unsigned short)a0;
    *(unsigned short*)(Sbuf + ((1*32768 + nb + e*2      ) ^ sw)) = (unsigned short)a1;
    *(unsigned short*)(Sbuf + ((2*32768 + nb + e*2      ) ^ sw)) = (unsigned short)a2;
    *(unsigned short*)(Sbuf + ((0*32768 + nb + 512 + e*2) ^ sw)) = (unsigned short)b0;
    *(unsigned short*)(Sbuf + ((1*32768 + nb + 512 + e*2) ^ sw)) = (unsigned short)b1;
    *(unsigned short*)(Sbuf + ((2*32768 + nb + 512 + e*2) ^ sw)) = (unsigned short)b2;
  }

  const s16x8 sgn = {(short)0x8000,(short)0x8000,(short)0x8000,(short)0x8000,
                     (short)0x8000,(short)0x8000,(short)0x8000,(short)0x8000};

  f32x4 accR[2][2], accI[2][2];

  #pragma unroll 1
  for (int layer = 0; layer < LAYERS; ++layer) {
    #pragma unroll
    for (int ms = 0; ms < 2; ++ms)
      #pragma unroll
      for (int ns = 0; ns < 2; ++ns) {
        accR[ms][ns] = (f32x4){0.f,0.f,0.f,0.f};
        accI[ms][ns] = (f32x4){0.f,0.f,0.f,0.f};
      }

    const char* wsl = ws + (size_t)layer * (size_t)(16*W_CHUNK);

    #pragma unroll 1
    for (int c8 = 0; c8 < 8; ++c8) {
      const char* wchunk = wsl + (size_t)c8 * (2*W_CHUNK);

      // ===== sub-phase 0: stage Wr chunk =====
      __syncthreads();                    // prior compute done with Wbuf (and S stable)
      {
        const char* src = wchunk + (wv*6)*1024 + lane*16;
        char* dst = Wbuf + (wv*6)*1024;   // wave-uniform LDS base, lane*16 implicit
        #pragma unroll
        for (int q = 0; q < 6; ++q)
          gload_lds16(src + q*1024, dst + q*1024);
      }
      __syncthreads();                    // barrier drains vmcnt -> W ready

      // B-frags (state) for this c8, both halves, used by both sub-phases.
      s16x8 xr[3][2], xi[3][2];
      #pragma unroll
      for (int sv = 0; sv < 3; ++sv)
        #pragma unroll
        for (int ns = 0; ns < 2; ++ns) {
          const u32 lin = (u32)(sv*32768 + (ns*16 + nloc)*1024 + (c8*32 + g*8)*2);
          xr[sv][ns] = *(const s16x8*)(Sbuf + ( lin        ^ swz));
          xi[sv][ns] = *(const s16x8*)(Sbuf + ((lin + 512) ^ swz));
        }

      // Cr += Wr*Xr ; Ci += Wr*Xi  (8 split-term pairs, drop lo*lo)
      #pragma unroll
      for (int ms = 0; ms < 2; ++ms) {
        const u32 rowoff = (u32)((m0 + ms*16 + nloc)*64 + g*16);
        #pragma unroll
        for (int su = 0; su < 3; ++su) {
          const s16x8 wf = *(const s16x8*)(Wbuf + (((u32)(su*16384) + rowoff) ^ swz));
          #pragma unroll
          for (int sv = 0; sv < 3; ++sv) {
            if (su + sv > 3) continue;
            #pragma unroll
            for (int ns = 0; ns < 2; ++ns) {
              accR[ms][ns] = __builtin_amdgcn_mfma_f32_16x16x32_bf16(wf, xr[sv][ns], accR[ms][ns], 0,0,0);
              accI[ms][ns] = __builtin_amdgcn_mfma_f32_16x16x32_bf16(wf, xi[sv][ns], accI[ms][ns], 0,0,0);
            }
          }
        }
      }

      // ===== sub-phase 1: stage Wi chunk =====
      __syncthreads();
      {
        const char* src = wchunk + W_CHUNK + (wv*6)*1024 + lane*16;
        char* dst = Wbuf + (wv*6)*1024;
        #pragma unroll
        for (int q = 0; q < 6; ++q)
          gload_lds16(src + q*1024, dst + q*1024);
      }
      __syncthreads();

      // Cr += (-Wi)*Xi ; Ci += Wi*Xr
      #pragma unroll
      for (int ms = 0; ms < 2; ++ms) {
        const u32 rowoff = (u32)((m0 + ms*16 + nloc)*64 + g*16);
        #pragma unroll
        for (int su = 0; su < 3; ++su) {
          const s16x8 wf  = *(const s16x8*)(Wbuf + (((u32)(su*16384) + rowoff) ^ swz));
          const s16x8 nwf = wf ^ sgn;   // negate bf16 signs
          #pragma unroll
          for (int sv = 0; sv < 3; ++sv) {
            if (su + sv > 3) continue;
            #pragma unroll
            for (int ns = 0; ns < 2; ++ns) {
              accR[ms][ns] = __builtin_amdgcn_mfma_f32_16x16x32_bf16(nwf, xi[sv][ns], accR[ms][ns], 0,0,0);
              accI[ms][ns] = __builtin_amdgcn_mfma_f32_16x16x32_bf16(wf,  xr[sv][ns], accI[ms][ns], 0,0,0);
            }
          }
        }
      }
    } // c8

    __syncthreads();   // all waves finished reading S for this layer

    if (layer < LAYERS - 1) {
      // epilogue: split new state, write S in place (own rows only)
      #pragma unroll
      for (int ms = 0; ms < 2; ++ms)
        #pragma unroll
        for (int ns = 0; ns < 2; ++ns) {
          const int n = ns*16 + nloc;
          const int row0 = m0 + ms*16 + g*4;
          u32 hr[4], mr[4], lr[4], hi2[4], mi2[4], li2[4];
          #pragma unroll
          for (int rr = 0; rr < 4; ++rr) {
            split3f(accR[ms][ns][rr], hr[rr], mr[rr], lr[rr]);
            split3f(accI[ms][ns][rr], hi2[rr], mi2[rr], li2[rr]);
          }
          const u32 baseR = (u32)(n*1024 + row0*2);
          const u32 baseI = baseR + 512;
          const u32 sw = (u32)((n & 7) << 4);
          u32 p0, p1;
          p0 = hr[0]  | (hr[1]  << 16); p1 = hr[2]  | (hr[3]  << 16);
          *(uint2*)(Sbuf + ((0*32768 + baseR) ^ sw)) = make_uint2(p0, p1);
          p0 = mr[0]  | (mr[1]  << 16); p1 = mr[2]  | (mr[3]  << 16);
          *(uint2*)(Sbuf + ((1*32768 + baseR) ^ sw)) = make_uint2(p0, p1);
          p0 = lr[0]  | (lr[1]  << 16); p1 = lr[2]  | (lr[3]  << 16);
          *(uint2*)(Sbuf + ((2*32768 + baseR) ^ sw)) = make_uint2(p0, p1);
          p0 = hi2[0] | (hi2[1] << 16); p1 = hi2[2] | (hi2[3] << 16);
          *(uint2*)(Sbuf + ((0*32768 + baseI) ^ sw)) = make_uint2(p0, p1);
          p0 = mi2[0] | (mi2[1] << 16); p1 = mi2[2] | (mi2[3] << 16);
          *(uint2*)(Sbuf + ((1*32768 + baseI) ^ sw)) = make_uint2(p0, p1);
          p0 = li2[0] | (li2[1] << 16); p1 = li2[2] | (li2[3] << 16);
          *(uint2*)(Sbuf + ((2*32768 + baseI) ^ sw)) = make_uint2(p0, p1);
        }
      // visibility for next layer covered by next c8-loop's first barrier
    } else {
      // final layer: write [B,16,16,2] output
      #pragma unroll
      for (int ms = 0; ms < 2; ++ms)
        #pragma unroll
        for (int ns = 0; ns < 2; ++ns) {
          const int n = ns*16 + nloc;
          const long b = sample_base + n;
          const int row0 = m0 + ms*16 + g*4;
          #pragma unroll
          for (int rr = 0; rr < 4; ++rr) {
            float2 v = make_float2(accR[ms][ns][rr], accI[ms][ns][rr]);
            *(float2*)(out + b*512 + (long)(row0+rr)*2) = v;
          }
        }
    }
  } // layer
}

// ---------------- fp32 fallback (proven-correct R3 baseline) ----------------
constexpr int SAMPLES_PER_BLOCK = 16;
constexpr int FB_THREADS = SAMPLES_PER_BLOCK * 16;
constexpr int U_STRIDE = 520;

__global__ __launch_bounds__(FB_THREADS, 3)
void hqmm_kernel(const float* __restrict__ sr, const float* __restrict__ si,
                 const float* __restrict__ kr, const float* __restrict__ ki,
                 float* __restrict__ out)
{
    __shared__ float2 AT[KOPS][16][16];
    __shared__ float  U[SAMPLES_PER_BLOCK * U_STRIDE];

    const int tid = threadIdx.x;
    const int s   = tid >> 4;
    const int c   = tid & 15;
    const long b  = (long)blockIdx.x * SAMPLES_PER_BLOCK + s;

    float rr[16], ri[16];
    const float* srb = sr + b * 256;
    const float* sib = si + b * 256;
#pragma unroll
    for (int j = 0; j < 16; ++j) { rr[j] = srb[j*16 + c]; ri[j] = sib[j*16 + c]; }

#pragma unroll 1
    for (int layer = 0; layer < LAYERS; ++layer) {
        const float* krl = kr + (size_t)layer * KOPS * 256;
        const float* kil = ki + (size_t)layer * KOPS * 256;
        for (int idx = tid; idx < KOPS*256; idx += FB_THREADS) {
            int k = idx >> 8, rem = idx & 255, l = rem >> 4, m = rem & 15;
            AT[k][l][m] = make_float2(krl[(k*16+m)*16+l], kil[(k*16+m)*16+l]);
        }
        float accr[16], acci[16];
#pragma unroll
        for (int i = 0; i < 16; ++i) { accr[i] = 0.f; acci[i] = 0.f; }
#pragma unroll 1
        for (int k = 0; k < KOPS; ++k) {
            const float* ka = krl + k*256;
            const float* kb = kil + k*256;
            float ur[16], ui[16];
#pragma unroll
            for (int i = 0; i < 16; ++i) {
                float xr = 0.f, xi = 0.f;
#pragma unroll
                for (int j = 0; j < 16; ++j) {
                    float ar = ka[i*16+j], ai = kb[i*16+j];
                    xr += ar*rr[j] - ai*ri[j];
                    xi += ar*ri[j] + ai*rr[j];
                }
                ur[i] = xr; ui[i] = xi;
            }
#pragma unroll
            for (int i = 0; i < 16; ++i) {
                int w = s*U_STRIDE + (i*16 + c)*2;
                U[w] = ur[i]; U[w+1] = ui[i];
            }
            __syncthreads();
#pragma unroll
            for (int lp = 0; lp < 8; ++lp) {
                float2 a0 = AT[k][2*lp][c];
                float2 a1 = AT[k][2*lp+1][c];
#pragma unroll
                for (int i = 0; i < 16; ++i) {
                    const float4 u = *reinterpret_cast<const float4*>(
                        &U[s*U_STRIDE + (i*16 + 2*lp)*2]);
                    accr[i] += u.x*a0.x + u.y*a0.y;
                    acci[i] += u.y*a0.x - u.x*a0.y;
                    accr[i] += u.z*a1.x + u.w*a1.y;
                    acci[i] += u.w*a1.x - u.z*a1.y;
                }
            }
            __syncthreads();
        }
#pragma unroll
        for (int i = 0; i < 16; ++i) { rr[i] = accr[i]; ri[i] = acci[i]; }
    }
    float2* o2 = reinterpret_cast<float2*>(out);
#pragma unroll
    for (int i = 0; i < 16; ++i)
        o2[(b*16 + i)*16 + c] = make_float2(rr[i], ri[i]);
}

// ---------------- host ----------------
extern "C" void kernel_launch(void* const* d_in, const int* in_sizes, int n_in,
                              void* d_out, int out_size, void* d_ws, size_t ws_size,
                              hipStream_t stream) {
    const float* sr = (const float*)d_in[0];
    const float* si = (const float*)d_in[1];
    const float* kr = (const float*)d_in[2];
    const float* ki = (const float*)d_in[3];
    float* out = (float*)d_out;

    if (ws_size >= W_TOTAL) {
        build_w<<<dim3(LAYERS*8), 256, 0, stream>>>(kr, ki, (char*)d_ws);
        hqmm_mfma<<<dim3(B_TOTAL/NT), MF_THREADS, 0, stream>>>(
            sr, si, (const char*)d_ws, out);
    } else {
        // scratch too small for the superoperator tables: proven fp32 path
        hqmm_kernel<<<dim3(B_TOTAL/SAMPLES_PER_BLOCK), FB_THREADS, 0, stream>>>(
            sr, si, kr, ki, out);
    }
}

// Round 8
// 602.226 us; speedup vs baseline: 7.1945x; 2.7665x over previous
//
#include <hip/hip_runtime.h>

constexpr int KOPS   = 5;
constexpr int LAYERS = 25;
constexpr int B_TOTAL = 16384;

typedef unsigned int u32;
using f32x4 = __attribute__((ext_vector_type(4))) float;
using s16x8 = __attribute__((ext_vector_type(8))) short;

// ---------------- helpers ----------------
__device__ __forceinline__ u32 rtn16(u32 u) {        // round-to-nearest bf16
  return u + 0x7FFFu + ((u >> 16) & 1u);
}
// 2-level RTN bf16 split: x ~= h + m, residual ~2^-18 relative.
__device__ __forceinline__ void split2f(float x, u32& h, u32& m) {
  u32 u0 = __float_as_uint(x);
  u32 hb = rtn16(u0) & 0xFFFF0000u;
  float r1 = x - __uint_as_float(hb);
  h = hb >> 16;
  m = rtn16(__float_as_uint(r1)) >> 16;
}
// 3-level split (fp32 fallback-grade), used nowhere hot now but kept for S init? no — 2-level everywhere.

// ---------------- MFMA path constants ----------------
constexpr int NT = 64;             // samples per block
constexpr int MF_THREADS = 512;    // 8 waves = 4 mgroups x 2 ngroups
// W table: [layer][c8][part(2)][su(2)][mtile(16)] x 1024B lane-ordered frags
constexpr size_t W_TOTAL = (size_t)LAYERS * 8 * 2 * 2 * 16 * 1024;  // 13,107,200 B

// ---------------- W precompute ----------------
// W[r=i*16+m][c=j*16+l] = sum_k A_k[i][j]*conj(A_k[m][l]), 2-level bf16 split,
// stored as contiguous per-(c8,part,su,mtile) 1KB fragments in exact MFMA
// A-operand lane order: byte = lane*16 + j*2, lane = (row&15) + (kk>>3)*16,
// element j = kk&7, kk = col within the 32-wide c8 chunk.
__global__ __launch_bounds__(256)
void build_w(const float* __restrict__ kr, const float* __restrict__ ki,
             char* __restrict__ ws)
{
  const int layer = blockIdx.x >> 3;
  const int c8    = blockIdx.x & 7;
  const int r     = threadIdx.x;          // output row 0..255
  __shared__ float Ar[KOPS*256];
  __shared__ float Ai[KOPS*256];
  for (int t = r; t < KOPS*256; t += 256) {
    Ar[t] = kr[layer*KOPS*256 + t];
    Ai[t] = ki[layer*KOPS*256 + t];
  }
  __syncthreads();
  const int i = r >> 4, m = r & 15;
  // fragment row base for (p,su): ((layer*8+c8)*4 + p*2+su)*16384 + mtile*1024
  char* const base = ws + (size_t)((layer*8 + c8)*4) * 16384 + (size_t)(r >> 4) * 1024;

  for (int mm = 0; mm < 16; ++mm) {
    const int kk0 = 2*mm, kk1 = 2*mm + 1;
    float wr[2], wi[2];
    #pragma unroll
    for (int q = 0; q < 2; ++q) {
      const int c = c8*32 + 2*mm + q;
      const int j = c >> 4, l = c & 15;
      float xr = 0.f, xi = 0.f;
      #pragma unroll
      for (int k = 0; k < KOPS; ++k) {
        float ar = Ar[k*256 + i*16 + j], ai = Ai[k*256 + i*16 + j];
        float br = Ar[k*256 + m*16 + l], bi = Ai[k*256 + m*16 + l];
        xr += ar*br + ai*bi;          // re(A * conj(B))
        xi += ai*br - ar*bi;          // im(A * conj(B))
      }
      wr[q] = xr; wi[q] = xi;
    }
    u32 rh0, rm0, rh1, rm1, ih0, im0, ih1, im1;
    split2f(wr[0], rh0, rm0);  split2f(wr[1], rh1, rm1);
    split2f(wi[0], ih0, im0);  split2f(wi[1], ih1, im1);
    const int lane = (r & 15) + ((kk0 >> 3) << 4);
    const u32 off  = (u32)(lane*16 + (kk0 & 7)*2);   // kk1 lands at off+2 (same u32)
    *(u32*)(base +     0 + off) = rh0 | (rh1 << 16);   // p0 su0
    *(u32*)(base + 16384 + off) = rm0 | (rm1 << 16);   // p0 su1
    *(u32*)(base + 32768 + off) = ih0 | (ih1 << 16);   // p1 su0
    *(u32*)(base + 49152 + off) = im0 | (im1 << 16);   // p1 su1
  }
}

// ---------------- main MFMA kernel ----------------
// 256 blocks x 64 samples. State S in LDS: 2 splits x [64 samples][512 elems
// = re256|im256] bf16, XOR-swizzled by ((n&7)<<4). W read per-fragment
// directly global->VGPR (contiguous 1KB coalesced loads, L2-resident table).
// c8 loop is barrier-free; 2 barriers per layer around the S update.
__global__ __launch_bounds__(MF_THREADS, 2)
void hqmm2(const float* __restrict__ sr, const float* __restrict__ si,
           const char* __restrict__ ws, float* __restrict__ out)
{
  __shared__ char Sbuf[131072];     // [sv][n][elem]: sv stride 65536, n stride 1024

  const int tid  = threadIdx.x;
  const int lane = tid & 63;
  const int wv   = tid >> 6;
  const int mg   = wv >> 1;          // 0..3: rows [mg*64, mg*64+64)
  const int ng   = wv & 1;           // 0..1: samples [ng*32, ng*32+32)
  const int nloc = lane & 15;
  const int g    = lane >> 4;
  const long sample_base = (long)blockIdx.x * NT;
  const u32 swz = (u32)((lane & 7) << 4);

  // ---- init: load fp32 state, 2-split, store to Sbuf (u32-packed) ----
  for (int t = tid; t < NT*128; t += MF_THREADS) {
    const int n  = t >> 7;
    const int e0 = (t & 127) * 2;
    const float2 vr = *(const float2*)(sr + (sample_base + n)*256 + e0);
    const float2 vi = *(const float2*)(si + (sample_base + n)*256 + e0);
    u32 h0,m0_,h1,m1_, p0,q0,p1,q1;
    split2f(vr.x, h0, m0_); split2f(vr.y, h1, m1_);
    split2f(vi.x, p0, q0);  split2f(vi.y, p1, q1);
    const u32 sw = (u32)((n & 7) << 4);
    const u32 nb = (u32)(n * 1024 + e0 * 2);
    *(u32*)(Sbuf + ((nb              ) ^ sw)) = h0  | (h1  << 16);
    *(u32*)(Sbuf + ((nb + 65536      ) ^ sw)) = m0_ | (m1_ << 16);
    *(u32*)(Sbuf + ((nb + 512        ) ^ sw)) = p0  | (p1  << 16);
    *(u32*)(Sbuf + ((nb + 65536 + 512) ^ sw)) = q0  | (q1  << 16);
  }
  __syncthreads();

  const s16x8 sgn = {(short)0x8000,(short)0x8000,(short)0x8000,(short)0x8000,
                     (short)0x8000,(short)0x8000,(short)0x8000,(short)0x8000};

  f32x4 aR[4][2], aI[4][2];

  #pragma unroll 1
  for (int layer = 0; layer < LAYERS; ++layer) {
    #pragma unroll
    for (int ms = 0; ms < 4; ++ms)
      #pragma unroll
      for (int ns = 0; ns < 2; ++ns) {
        aR[ms][ns] = (f32x4){0.f,0.f,0.f,0.f};
        aI[ms][ns] = (f32x4){0.f,0.f,0.f,0.f};
      }

    const char* const wsl = ws + (size_t)layer * (8 * 65536);

    #pragma unroll 1
    for (int c8 = 0; c8 < 8; ++c8) {
      // X fragments (8 ds_read_b128): [ns][ri], splits h/m
      s16x8 xh[2][2], xm[2][2];
      #pragma unroll
      for (int ns = 0; ns < 2; ++ns) {
        const u32 lin = (u32)((((ng*2 + ns)*16 + nloc)*1024) + (c8*32 + g*8)*2);
        xh[ns][0] = *(const s16x8*)(Sbuf + ((lin              ) ^ swz));
        xh[ns][1] = *(const s16x8*)(Sbuf + ((lin + 512        ) ^ swz));
        xm[ns][0] = *(const s16x8*)(Sbuf + ((lin + 65536      ) ^ swz));
        xm[ns][1] = *(const s16x8*)(Sbuf + ((lin + 65536 + 512) ^ swz));
      }
      // W fragments: contiguous 1KB per frag, wave reads its 4 mtiles
      const char* const wb = wsl + (size_t)c8 * 65536 + (size_t)(mg*4) * 1024
                                 + (size_t)lane * 16;
      #pragma unroll
      for (int ms = 0; ms < 4; ++ms) {
        const s16x8 wrh = *(const s16x8*)(wb +         ms*1024);
        const s16x8 wrm = *(const s16x8*)(wb + 16384 + ms*1024);
        const s16x8 wih = *(const s16x8*)(wb + 32768 + ms*1024);
        const s16x8 wim = *(const s16x8*)(wb + 49152 + ms*1024);
        const s16x8 nwih = wih ^ sgn;
        const s16x8 nwim = wim ^ sgn;
        #pragma unroll
        for (int ns = 0; ns < 2; ++ns) {
          // hh terms
          aR[ms][ns] = __builtin_amdgcn_mfma_f32_16x16x32_bf16(wrh,  xh[ns][0], aR[ms][ns], 0,0,0);
          aI[ms][ns] = __builtin_amdgcn_mfma_f32_16x16x32_bf16(wrh,  xh[ns][1], aI[ms][ns], 0,0,0);
          aR[ms][ns] = __builtin_amdgcn_mfma_f32_16x16x32_bf16(nwih, xh[ns][1], aR[ms][ns], 0,0,0);
          aI[ms][ns] = __builtin_amdgcn_mfma_f32_16x16x32_bf16(wih,  xh[ns][0], aI[ms][ns], 0,0,0);
          // mh terms (W-mid x X-hi)
          aR[ms][ns] = __builtin_amdgcn_mfma_f32_16x16x32_bf16(wrm,  xh[ns][0], aR[ms][ns], 0,0,0);
          aI[ms][ns] = __builtin_amdgcn_mfma_f32_16x16x32_bf16(wrm,  xh[ns][1], aI[ms][ns], 0,0,0);
          aR[ms][ns] = __builtin_amdgcn_mfma_f32_16x16x32_bf16(nwim, xh[ns][1], aR[ms][ns], 0,0,0);
          aI[ms][ns] = __builtin_amdgcn_mfma_f32_16x16x32_bf16(wim,  xh[ns][0], aI[ms][ns], 0,0,0);
          // hm terms (W-hi x X-mid)
          aR[ms][ns] = __builtin_amdgcn_mfma_f32_16x16x32_bf16(wrh,  xm[ns][0], aR[ms][ns], 0,0,0);
          aI[ms][ns] = __builtin_amdgcn_mfma_f32_16x16x32_bf16(wrh,  xm[ns][1], aI[ms][ns], 0,0,0);
          aR[ms][ns] = __builtin_amdgcn_mfma_f32_16x16x32_bf16(nwih, xm[ns][1], aR[ms][ns], 0,0,0);
          aI[ms][ns] = __builtin_amdgcn_mfma_f32_16x16x32_bf16(wih,  xm[ns][0], aI[ms][ns], 0,0,0);
        }
      }
    } // c8

    __syncthreads();   // all waves done reading S this layer

    if (layer < LAYERS - 1) {
      // write new state (2-split), own (rows x samples) region only
      #pragma unroll
      for (int ms = 0; ms < 4; ++ms)
        #pragma unroll
        for (int ns = 0; ns < 2; ++ns) {
          const int n = (ng*2 + ns)*16 + nloc;
          const u32 sw = (u32)((n & 7) << 4);
          const u32 baseR = (u32)(n*1024 + ((mg*4 + ms)*16 + g*4)*2);
          u32 h[4], m[4], hi2[4], mi2[4];
          #pragma unroll
          for (int rr = 0; rr < 4; ++rr) {
            split2f(aR[ms][ns][rr], h[rr],  m[rr]);
            split2f(aI[ms][ns][rr], hi2[rr], mi2[rr]);
          }
          *(uint2*)(Sbuf + ((baseR              ) ^ sw)) =
              make_uint2(h[0]  | (h[1]  << 16), h[2]  | (h[3]  << 16));
          *(uint2*)(Sbuf + ((baseR + 65536      ) ^ sw)) =
              make_uint2(m[0]  | (m[1]  << 16), m[2]  | (m[3]  << 16));
          *(uint2*)(Sbuf + ((baseR + 512        ) ^ sw)) =
              make_uint2(hi2[0]| (hi2[1]<< 16), hi2[2]| (hi2[3]<< 16));
          *(uint2*)(Sbuf + ((baseR + 65536 + 512) ^ sw)) =
              make_uint2(mi2[0]| (mi2[1]<< 16), mi2[2]| (mi2[3]<< 16));
        }
      __syncthreads(); // writes visible before next layer's reads
    } else {
      // final layer: out[b][row][2] = (re, im)
      #pragma unroll
      for (int ms = 0; ms < 4; ++ms)
        #pragma unroll
        for (int ns = 0; ns < 2; ++ns) {
          const int n = (ng*2 + ns)*16 + nloc;
          const long b = sample_base + n;
          const int row0 = (mg*4 + ms)*16 + g*4;
          #pragma unroll
          for (int rr = 0; rr < 4; ++rr) {
            *(float2*)(out + b*512 + (long)(row0 + rr)*2) =
                make_float2(aR[ms][ns][rr], aI[ms][ns][rr]);
          }
        }
    }
  } // layer
}

// ---------------- fp32 fallback (proven-correct R3 baseline) ----------------
constexpr int SAMPLES_PER_BLOCK = 16;
constexpr int FB_THREADS = SAMPLES_PER_BLOCK * 16;
constexpr int U_STRIDE = 520;

__global__ __launch_bounds__(FB_THREADS, 3)
void hqmm_kernel(const float* __restrict__ sr, const float* __restrict__ si,
                 const float* __restrict__ kr, const float* __restrict__ ki,
                 float* __restrict__ out)
{
    __shared__ float2 AT[KOPS][16][16];
    __shared__ float  U[SAMPLES_PER_BLOCK * U_STRIDE];

    const int tid = threadIdx.x;
    const int s   = tid >> 4;
    const int c   = tid & 15;
    const long b  = (long)blockIdx.x * SAMPLES_PER_BLOCK + s;

    float rr[16], ri[16];
    const float* srb = sr + b * 256;
    const float* sib = si + b * 256;
#pragma unroll
    for (int j = 0; j < 16; ++j) { rr[j] = srb[j*16 + c]; ri[j] = sib[j*16 + c]; }

#pragma unroll 1
    for (int layer = 0; layer < LAYERS; ++layer) {
        const float* krl = kr + (size_t)layer * KOPS * 256;
        const float* kil = ki + (size_t)layer * KOPS * 256;
        for (int idx = tid; idx < KOPS*256; idx += FB_THREADS) {
            int k = idx >> 8, rem = idx & 255, l = rem >> 4, m = rem & 15;
            AT[k][l][m] = make_float2(krl[(k*16+m)*16+l], kil[(k*16+m)*16+l]);
        }
        float accr[16], acci[16];
#pragma unroll
        for (int i = 0; i < 16; ++i) { accr[i] = 0.f; acci[i] = 0.f; }
#pragma unroll 1
        for (int k = 0; k < KOPS; ++k) {
            const float* ka = krl + k*256;
            const float* kb = kil + k*256;
            float ur[16], ui[16];
#pragma unroll
            for (int i = 0; i < 16; ++i) {
                float xr = 0.f, xi = 0.f;
#pragma unroll
                for (int j = 0; j < 16; ++j) {
                    float ar = ka[i*16+j], ai = kb[i*16+j];
                    xr += ar*rr[j] - ai*ri[j];
                    xi += ar*ri[j] + ai*rr[j];
                }
                ur[i] = xr; ui[i] = xi;
            }
#pragma unroll
            for (int i = 0; i < 16; ++i) {
                int w = s*U_STRIDE + (i*16 + c)*2;
                U[w] = ur[i]; U[w+1] = ui[i];
            }
            __syncthreads();
#pragma unroll
            for (int lp = 0; lp < 8; ++lp) {
                float2 a0 = AT[k][2*lp][c];
                float2 a1 = AT[k][2*lp+1][c];
#pragma unroll
                for (int i = 0; i < 16; ++i) {
                    const float4 u = *reinterpret_cast<const float4*>(
                        &U[s*U_STRIDE + (i*16 + 2*lp)*2]);
                    accr[i] += u.x*a0.x + u.y*a0.y;
                    acci[i] += u.y*a0.x - u.x*a0.y;
                    accr[i] += u.z*a1.x + u.w*a1.y;
                    acci[i] += u.w*a1.x - u.z*a1.y;
                }
            }
            __syncthreads();
        }
#pragma unroll
        for (int i = 0; i < 16; ++i) { rr[i] = accr[i]; ri[i] = acci[i]; }
    }
    float2* o2 = reinterpret_cast<float2*>(out);
#pragma unroll
    for (int i = 0; i < 16; ++i)
        o2[(b*16 + i)*16 + c] = make_float2(rr[i], ri[i]);
}

// ---------------- host ----------------
extern "C" void kernel_launch(void* const* d_in, const int* in_sizes, int n_in,
                              void* d_out, int out_size, void* d_ws, size_t ws_size,
                              hipStream_t stream) {
    const float* sr = (const float*)d_in[0];
    const float* si = (const float*)d_in[1];
    const float* kr = (const float*)d_in[2];
    const float* ki = (const float*)d_in[3];
    float* out = (float*)d_out;

    if (ws_size >= W_TOTAL) {
        build_w<<<dim3(LAYERS*8), 256, 0, stream>>>(kr, ki, (char*)d_ws);
        hqmm2<<<dim3(B_TOTAL/NT), MF_THREADS, 0, stream>>>(
            sr, si, (const char*)d_ws, out);
    } else {
        hqmm_kernel<<<dim3(B_TOTAL/SAMPLES_PER_BLOCK), FB_THREADS, 0, stream>>>(
            sr, si, kr, ki, out);
    }
}

// Round 10
// 267.714 us; speedup vs baseline: 16.1841x; 2.2495x over previous
//
#include <hip/hip_runtime.h>

constexpr int KOPS   = 5;
constexpr int LAYERS = 25;
constexpr int B_TOTAL = 16384;

typedef unsigned int u32;
using f32x4 = __attribute__((ext_vector_type(4))) float;
using s16x8 = __attribute__((ext_vector_type(8))) short;

// ---------------- helpers ----------------
__device__ __forceinline__ u32 rtn16(u32 u) {        // round-to-nearest bf16
  return u + 0x7FFFu + ((u >> 16) & 1u);
}
// 2-level RTN bf16 split: x ~= h + m, residual ~2^-18 relative.
__device__ __forceinline__ void split2f(float x, u32& h, u32& m) {
  u32 u0 = __float_as_uint(x);
  u32 hb = rtn16(u0) & 0xFFFF0000u;
  float r1 = x - __uint_as_float(hb);
  h = hb >> 16;
  m = rtn16(__float_as_uint(r1)) >> 16;
}

// ---------------- table format (R8-proven) ----------------
// Per table (one 256x256 complex superop), 512 KB = 8 c8-chunks x 64 KB.
// u16 address of (row, col, plane): slot + (col>>5)*65536 + plane*16384
//   + (row>>4)*1024 + (row&15)*16 + ((col>>3)&3)*256 + (col&7)*2
// planes: 0 = re-hi, 1 = re-mid, 2 = im-hi, 3 = im-mid.
constexpr size_t SLOT = 524288;
constexpr size_t W_TOTAL = (size_t)LAYERS * SLOT;   // 13,107,200 B

// ---------------- per-layer W build (unchanged from R8, proven) ----------------
// W[r=i*16+m][c=j*16+l] = sum_k A_k[i][j]*conj(A_k[m][l])
__global__ __launch_bounds__(256)
void build_w(const float* __restrict__ kr, const float* __restrict__ ki,
             char* __restrict__ ws)
{
  const int layer = blockIdx.x >> 3;
  const int c8    = blockIdx.x & 7;
  const int r     = threadIdx.x;          // output row 0..255
  __shared__ float Ar[KOPS*256];
  __shared__ float Ai[KOPS*256];
  for (int t = r; t < KOPS*256; t += 256) {
    Ar[t] = kr[layer*KOPS*256 + t];
    Ai[t] = ki[layer*KOPS*256 + t];
  }
  __syncthreads();
  const int i = r >> 4, m = r & 15;
  char* const base = ws + (size_t)layer * SLOT + (size_t)c8 * 65536
                        + (size_t)(r >> 4) * 1024;
  for (int mm = 0; mm < 16; ++mm) {
    float wr[2], wi[2];
    #pragma unroll
    for (int q = 0; q < 2; ++q) {
      const int c = c8*32 + 2*mm + q;
      const int j = c >> 4, l = c & 15;
      float xr = 0.f, xi = 0.f;
      #pragma unroll
      for (int k = 0; k < KOPS; ++k) {
        float ar = Ar[k*256 + i*16 + j], ai = Ai[k*256 + i*16 + j];
        float br = Ar[k*256 + m*16 + l], bi = Ai[k*256 + m*16 + l];
        xr += ar*br + ai*bi;          // re(A * conj(B))
        xi += ai*br - ar*bi;          // im(A * conj(B))
      }
      wr[q] = xr; wi[q] = xi;
    }
    u32 rh0, rm0, rh1, rm1, ih0, im0, ih1, im1;
    split2f(wr[0], rh0, rm0);  split2f(wr[1], rh1, rm1);
    split2f(wi[0], ih0, im0);  split2f(wi[1], ih1, im1);
    const int kk0 = 2*mm;
    const int lane = (r & 15) + ((kk0 >> 3) << 4);
    const u32 off  = (u32)(lane*16 + (kk0 & 7)*2);
    *(u32*)(base +     0 + off) = rh0 | (rh1 << 16);
    *(u32*)(base + 16384 + off) = rm0 | (rm1 << 16);
    *(u32*)(base + 32768 + off) = ih0 | (ih1 << 16);
    *(u32*)(base + 49152 + off) = im0 | (im1 << 16);
  }
}

// ---------------- compose: P = LEFT * RIGHT (256x256 complex) ----------------
// Pass over item list: item j at slot j*stride; pair i: right=slot 2i*stride,
// left=slot (2i+1)*stride, out written IN PLACE over right slot. Each block
// handles 64 output cols: stages right's cols into Sbuf (B-layout), runs the
// R8 c8-loop with left's A-frags, scatters C back into table frag format.
__global__ __launch_bounds__(512)
void compose(char* __restrict__ ws, int stride, int npairs)
{
  __shared__ char Sbuf[131072];
  const int pair  = blockIdx.x >> 2;
  const int chunk = blockIdx.x & 3;
  const char* right = ws + (size_t)(2*pair)   * stride * SLOT;
  const char* left  = ws + (size_t)(2*pair+1) * stride * SLOT;
  char* outp        = ws + (size_t)(2*pair)   * stride * SLOT;

  const int tid  = threadIdx.x;
  const int lane = tid & 63;
  const int wv   = tid >> 6;
  const int mg   = wv >> 1;
  const int ng   = wv & 1;
  const int nloc = lane & 15;
  const int g    = lane >> 4;
  const u32 swz = (u32)((lane & 7) << 4);

  // ---- stage right cols [chunk*64, chunk*64+64) into Sbuf B-layout ----
  for (int idx = tid; idx < 8192; idx += 512) {
    const int e     = idx & 255;          // row of RIGHT (k-dim)
    const int oct   = (idx >> 8) & 7;     // 8-col group
    const int plane = idx >> 11;
    const int col0  = chunk*64 + oct*8;
    const s16x8 v = *(const s16x8*)(right + (size_t)(col0 >> 5)*65536
                      + (size_t)plane*16384 + (size_t)(e >> 4)*1024
                      + (size_t)((e & 15)*16) + (size_t)(((col0 >> 3) & 3)*256));
    const u32 dbase = ((plane & 1) ? 65536u : 0u) + ((plane & 2) ? 512u : 0u)
                      + (u32)(oct*8*1024) + (u32)(e*2);
    #pragma unroll
    for (int t = 0; t < 8; ++t) {
      *(unsigned short*)(Sbuf + ((dbase + (u32)(t*1024)) ^ ((u32)t << 4))) =
          (unsigned short)v[t];
    }
  }
  __syncthreads();

  const s16x8 sgn = {(short)0x8000,(short)0x8000,(short)0x8000,(short)0x8000,
                     (short)0x8000,(short)0x8000,(short)0x8000,(short)0x8000};
  f32x4 aR[4][2], aI[4][2];
  #pragma unroll
  for (int ms = 0; ms < 4; ++ms)
    #pragma unroll
    for (int ns = 0; ns < 2; ++ns) {
      aR[ms][ns] = (f32x4){0.f,0.f,0.f,0.f};
      aI[ms][ns] = (f32x4){0.f,0.f,0.f,0.f};
    }

  #pragma unroll 1
  for (int c8 = 0; c8 < 8; ++c8) {
    s16x8 xh[2][2], xm[2][2];
    #pragma unroll
    for (int ns = 0; ns < 2; ++ns) {
      const u32 lin = (u32)((((ng*2 + ns)*16 + nloc)*1024) + (c8*32 + g*8)*2);
      xh[ns][0] = *(const s16x8*)(Sbuf + ((lin              ) ^ swz));
      xh[ns][1] = *(const s16x8*)(Sbuf + ((lin + 512        ) ^ swz));
      xm[ns][0] = *(const s16x8*)(Sbuf + ((lin + 65536      ) ^ swz));
      xm[ns][1] = *(const s16x8*)(Sbuf + ((lin + 65536 + 512) ^ swz));
    }
    const char* const wb = left + (size_t)c8 * 65536 + (size_t)(mg*4) * 1024
                               + (size_t)lane * 16;
    #pragma unroll
    for (int ms = 0; ms < 4; ++ms) {
      const s16x8 wrh = *(const s16x8*)(wb +         ms*1024);
      const s16x8 wrm = *(const s16x8*)(wb + 16384 + ms*1024);
      const s16x8 wih = *(const s16x8*)(wb + 32768 + ms*1024);
      const s16x8 wim = *(const s16x8*)(wb + 49152 + ms*1024);
      const s16x8 nwih = wih ^ sgn;
      const s16x8 nwim = wim ^ sgn;
      #pragma unroll
      for (int ns = 0; ns < 2; ++ns) {
        aR[ms][ns] = __builtin_amdgcn_mfma_f32_16x16x32_bf16(wrh,  xh[ns][0], aR[ms][ns], 0,0,0);
        aI[ms][ns] = __builtin_amdgcn_mfma_f32_16x16x32_bf16(wrh,  xh[ns][1], aI[ms][ns], 0,0,0);
        aR[ms][ns] = __builtin_amdgcn_mfma_f32_16x16x32_bf16(nwih, xh[ns][1], aR[ms][ns], 0,0,0);
        aI[ms][ns] = __builtin_amdgcn_mfma_f32_16x16x32_bf16(wih,  xh[ns][0], aI[ms][ns], 0,0,0);
        aR[ms][ns] = __builtin_amdgcn_mfma_f32_16x16x32_bf16(wrm,  xh[ns][0], aR[ms][ns], 0,0,0);
        aI[ms][ns] = __builtin_amdgcn_mfma_f32_16x16x32_bf16(wrm,  xh[ns][1], aI[ms][ns], 0,0,0);
        aR[ms][ns] = __builtin_amdgcn_mfma_f32_16x16x32_bf16(nwim, xh[ns][1], aR[ms][ns], 0,0,0);
        aI[ms][ns] = __builtin_amdgcn_mfma_f32_16x16x32_bf16(wim,  xh[ns][0], aI[ms][ns], 0,0,0);
        aR[ms][ns] = __builtin_amdgcn_mfma_f32_16x16x32_bf16(wrh,  xm[ns][0], aR[ms][ns], 0,0,0);
        aI[ms][ns] = __builtin_amdgcn_mfma_f32_16x16x32_bf16(wrh,  xm[ns][1], aI[ms][ns], 0,0,0);
        aR[ms][ns] = __builtin_amdgcn_mfma_f32_16x16x32_bf16(nwih, xm[ns][1], aR[ms][ns], 0,0,0);
        aI[ms][ns] = __builtin_amdgcn_mfma_f32_16x16x32_bf16(wih,  xm[ns][0], aI[ms][ns], 0,0,0);
      }
    }
  }

  // ---- epilogue: scatter C into out table frag format (2-split) ----
  #pragma unroll
  for (int ms = 0; ms < 4; ++ms)
    #pragma unroll
    for (int ns = 0; ns < 2; ++ns) {
      const int col = chunk*64 + (ng*2 + ns)*16 + nloc;
      char* ob = outp + (size_t)(col >> 5)*65536 + (size_t)(mg*4 + ms)*1024
                      + (size_t)(((col >> 3) & 3)*256) + (size_t)((col & 7)*2);
      #pragma unroll
      for (int rr = 0; rr < 4; ++rr) {
        u32 h, m, hi, mi;
        split2f(aR[ms][ns][rr], h, m);
        split2f(aI[ms][ns][rr], hi, mi);
        const u32 ro = (u32)((g*4 + rr)*16);
        *(unsigned short*)(ob + ro)         = (unsigned short)h;
        *(unsigned short*)(ob + 16384 + ro) = (unsigned short)m;
        *(unsigned short*)(ob + 32768 + ro) = (unsigned short)hi;
        *(unsigned short*)(ob + 49152 + ro) = (unsigned short)mi;
      }
    }
}

// ---------------- apply kernel (R8 hqmm2 with runtime nlayers) ----------------
__global__ __launch_bounds__(512, 2)
void hqmm2(const float* __restrict__ sr, const float* __restrict__ si,
           const char* __restrict__ ws, float* __restrict__ out, int nlayers)
{
  __shared__ char Sbuf[131072];

  const int tid  = threadIdx.x;
  const int lane = tid & 63;
  const int wv   = tid >> 6;
  const int mg   = wv >> 1;
  const int ng   = wv & 1;
  const int nloc = lane & 15;
  const int g    = lane >> 4;
  const long sample_base = (long)blockIdx.x * 64;
  const u32 swz = (u32)((lane & 7) << 4);

  for (int t = tid; t < 64*128; t += 512) {
    const int n  = t >> 7;
    const int e0 = (t & 127) * 2;
    const float2 vr = *(const float2*)(sr + (sample_base + n)*256 + e0);
    const float2 vi = *(const float2*)(si + (sample_base + n)*256 + e0);
    u32 h0,m0_,h1,m1_, p0,q0,p1,q1;
    split2f(vr.x, h0, m0_); split2f(vr.y, h1, m1_);
    split2f(vi.x, p0, q0);  split2f(vi.y, p1, q1);
    const u32 sw = (u32)((n & 7) << 4);
    const u32 nb = (u32)(n * 1024 + e0 * 2);
    *(u32*)(Sbuf + ((nb              ) ^ sw)) = h0  | (h1  << 16);
    *(u32*)(Sbuf + ((nb + 65536      ) ^ sw)) = m0_ | (m1_ << 16);
    *(u32*)(Sbuf + ((nb + 512        ) ^ sw)) = p0  | (p1  << 16);
    *(u32*)(Sbuf + ((nb + 65536 + 512) ^ sw)) = q0  | (q1  << 16);
  }
  __syncthreads();

  const s16x8 sgn = {(short)0x8000,(short)0x8000,(short)0x8000,(short)0x8000,
                     (short)0x8000,(short)0x8000,(short)0x8000,(short)0x8000};
  f32x4 aR[4][2], aI[4][2];

  #pragma unroll 1
  for (int layer = 0; layer < nlayers; ++layer) {
    #pragma unroll
    for (int ms = 0; ms < 4; ++ms)
      #pragma unroll
      for (int ns = 0; ns < 2; ++ns) {
        aR[ms][ns] = (f32x4){0.f,0.f,0.f,0.f};
        aI[ms][ns] = (f32x4){0.f,0.f,0.f,0.f};
      }
    const char* const wsl = ws + (size_t)layer * SLOT;

    #pragma unroll 1
    for (int c8 = 0; c8 < 8; ++c8) {
      s16x8 xh[2][2], xm[2][2];
      #pragma unroll
      for (int ns = 0; ns < 2; ++ns) {
        const u32 lin = (u32)((((ng*2 + ns)*16 + nloc)*1024) + (c8*32 + g*8)*2);
        xh[ns][0] = *(const s16x8*)(Sbuf + ((lin              ) ^ swz));
        xh[ns][1] = *(const s16x8*)(Sbuf + ((lin + 512        ) ^ swz));
        xm[ns][0] = *(const s16x8*)(Sbuf + ((lin + 65536      ) ^ swz));
        xm[ns][1] = *(const s16x8*)(Sbuf + ((lin + 65536 + 512) ^ swz));
      }
      const char* const wb = wsl + (size_t)c8 * 65536 + (size_t)(mg*4) * 1024
                                 + (size_t)lane * 16;
      #pragma unroll
      for (int ms = 0; ms < 4; ++ms) {
        const s16x8 wrh = *(const s16x8*)(wb +         ms*1024);
        const s16x8 wrm = *(const s16x8*)(wb + 16384 + ms*1024);
        const s16x8 wih = *(const s16x8*)(wb + 32768 + ms*1024);
        const s16x8 wim = *(const s16x8*)(wb + 49152 + ms*1024);
        const s16x8 nwih = wih ^ sgn;
        const s16x8 nwim = wim ^ sgn;
        #pragma unroll
        for (int ns = 0; ns < 2; ++ns) {
          aR[ms][ns] = __builtin_amdgcn_mfma_f32_16x16x32_bf16(wrh,  xh[ns][0], aR[ms][ns], 0,0,0);
          aI[ms][ns] = __builtin_amdgcn_mfma_f32_16x16x32_bf16(wrh,  xh[ns][1], aI[ms][ns], 0,0,0);
          aR[ms][ns] = __builtin_amdgcn_mfma_f32_16x16x32_bf16(nwih, xh[ns][1], aR[ms][ns], 0,0,0);
          aI[ms][ns] = __builtin_amdgcn_mfma_f32_16x16x32_bf16(wih,  xh[ns][0], aI[ms][ns], 0,0,0);
          aR[ms][ns] = __builtin_amdgcn_mfma_f32_16x16x32_bf16(wrm,  xh[ns][0], aR[ms][ns], 0,0,0);
          aI[ms][ns] = __builtin_amdgcn_mfma_f32_16x16x32_bf16(wrm,  xh[ns][1], aI[ms][ns], 0,0,0);
          aR[ms][ns] = __builtin_amdgcn_mfma_f32_16x16x32_bf16(nwim, xh[ns][1], aR[ms][ns], 0,0,0);
          aI[ms][ns] = __builtin_amdgcn_mfma_f32_16x16x32_bf16(wim,  xh[ns][0], aI[ms][ns], 0,0,0);
          aR[ms][ns] = __builtin_amdgcn_mfma_f32_16x16x32_bf16(wrh,  xm[ns][0], aR[ms][ns], 0,0,0);
          aI[ms][ns] = __builtin_amdgcn_mfma_f32_16x16x32_bf16(wrh,  xm[ns][1], aI[ms][ns], 0,0,0);
          aR[ms][ns] = __builtin_amdgcn_mfma_f32_16x16x32_bf16(nwih, xm[ns][1], aR[ms][ns], 0,0,0);
          aI[ms][ns] = __builtin_amdgcn_mfma_f32_16x16x32_bf16(wih,  xm[ns][0], aI[ms][ns], 0,0,0);
        }
      }
    } // c8

    __syncthreads();

    if (layer < nlayers - 1) {
      #pragma unroll
      for (int ms = 0; ms < 4; ++ms)
        #pragma unroll
        for (int ns = 0; ns < 2; ++ns) {
          const int n = (ng*2 + ns)*16 + nloc;
          const u32 sw = (u32)((n & 7) << 4);
          const u32 baseR = (u32)(n*1024 + ((mg*4 + ms)*16 + g*4)*2);
          u32 h[4], m[4], hi2[4], mi2[4];
          #pragma unroll
          for (int rr = 0; rr < 4; ++rr) {
            split2f(aR[ms][ns][rr], h[rr],  m[rr]);
            split2f(aI[ms][ns][rr], hi2[rr], mi2[rr]);
          }
          *(uint2*)(Sbuf + ((baseR              ) ^ sw)) =
              make_uint2(h[0]  | (h[1]  << 16), h[2]  | (h[3]  << 16));
          *(uint2*)(Sbuf + ((baseR + 65536      ) ^ sw)) =
              make_uint2(m[0]  | (m[1]  << 16), m[2]  | (m[3]  << 16));
          *(uint2*)(Sbuf + ((baseR + 512        ) ^ sw)) =
              make_uint2(hi2[0]| (hi2[1]<< 16), hi2[2]| (hi2[3]<< 16));
          *(uint2*)(Sbuf + ((baseR + 65536 + 512) ^ sw)) =
              make_uint2(mi2[0]| (mi2[1]<< 16), mi2[2]| (mi2[3]<< 16));
        }
      __syncthreads();
    } else {
      #pragma unroll
      for (int ms = 0; ms < 4; ++ms)
        #pragma unroll
        for (int ns = 0; ns < 2; ++ns) {
          const int n = (ng*2 + ns)*16 + nloc;
          const long b = sample_base + n;
          const int row0 = (mg*4 + ms)*16 + g*4;
          #pragma unroll
          for (int rr = 0; rr < 4; ++rr) {
            *(float2*)(out + b*512 + (long)(row0 + rr)*2) =
                make_float2(aR[ms][ns][rr], aI[ms][ns][rr]);
          }
        }
    }
  } // layer
}

// ---------------- fp32 fallback (proven-correct R3 baseline) ----------------
constexpr int SAMPLES_PER_BLOCK = 16;
constexpr int FB_THREADS = SAMPLES_PER_BLOCK * 16;
constexpr int U_STRIDE = 520;

__global__ __launch_bounds__(FB_THREADS, 3)
void hqmm_kernel(const float* __restrict__ sr, const float* __restrict__ si,
                 const float* __restrict__ kr, const float* __restrict__ ki,
                 float* __restrict__ out)
{
    __shared__ float2 AT[KOPS][16][16];
    __shared__ float  U[SAMPLES_PER_BLOCK * U_STRIDE];

    const int tid = threadIdx.x;
    const int s   = tid >> 4;
    const int c   = tid & 15;
    const long b  = (long)blockIdx.x * SAMPLES_PER_BLOCK + s;

    float rr[16], ri[16];
    const float* srb = sr + b * 256;
    const float* sib = si + b * 256;
#pragma unroll
    for (int j = 0; j < 16; ++j) { rr[j] = srb[j*16 + c]; ri[j] = sib[j*16 + c]; }

#pragma unroll 1
    for (int layer = 0; layer < LAYERS; ++layer) {
        const float* krl = kr + (size_t)layer * KOPS * 256;
        const float* kil = ki + (size_t)layer * KOPS * 256;
        for (int idx = tid; idx < KOPS*256; idx += FB_THREADS) {
            int k = idx >> 8, rem = idx & 255, l = rem >> 4, m = rem & 15;
            AT[k][l][m] = make_float2(krl[(k*16+m)*16+l], kil[(k*16+m)*16+l]);
        }
        float accr[16], acci[16];
#pragma unroll
        for (int i = 0; i < 16; ++i) { accr[i] = 0.f; acci[i] = 0.f; }
#pragma unroll 1
        for (int k = 0; k < KOPS; ++k) {
            const float* ka = krl + k*256;
            const float* kb = kil + k*256;
            float ur[16], ui[16];
#pragma unroll
            for (int i = 0; i < 16; ++i) {
                float xr = 0.f, xi = 0.f;
#pragma unroll
                for (int j = 0; j < 16; ++j) {
                    float ar = ka[i*16+j], ai = kb[i*16+j];
                    xr += ar*rr[j] - ai*ri[j];
                    xi += ar*ri[j] + ai*rr[j];
                }
                ur[i] = xr; ui[i] = xi;
            }
#pragma unroll
            for (int i = 0; i < 16; ++i) {
                int w = s*U_STRIDE + (i*16 + c)*2;
                U[w] = ur[i]; U[w+1] = ui[i];
            }
            __syncthreads();
#pragma unroll
            for (int lp = 0; lp < 8; ++lp) {
                float2 a0 = AT[k][2*lp][c];
                float2 a1 = AT[k][2*lp+1][c];
#pragma unroll
                for (int i = 0; i < 16; ++i) {
                    const float4 u = *reinterpret_cast<const float4*>(
                        &U[s*U_STRIDE + (i*16 + 2*lp)*2]);
                    accr[i] += u.x*a0.x + u.y*a0.y;
                    acci[i] += u.y*a0.x - u.x*a0.y;
                    accr[i] += u.z*a1.x + u.w*a1.y;
                    acci[i] += u.w*a1.x - u.z*a1.y;
                }
            }
            __syncthreads();
        }
#pragma unroll
        for (int i = 0; i < 16; ++i) { rr[i] = accr[i]; ri[i] = acci[i]; }
    }
    float2* o2 = reinterpret_cast<float2*>(out);
#pragma unroll
    for (int i = 0; i < 16; ++i)
        o2[(b*16 + i)*16 + c] = make_float2(rr[i], ri[i]);
}

// ---------------- host ----------------
extern "C" void kernel_launch(void* const* d_in, const int* in_sizes, int n_in,
                              void* d_out, int out_size, void* d_ws, size_t ws_size,
                              hipStream_t stream) {
    const float* sr = (const float*)d_in[0];
    const float* si = (const float*)d_in[1];
    const float* kr = (const float*)d_in[2];
    const float* ki = (const float*)d_in[3];
    float* out = (float*)d_out;

    if (ws_size >= W_TOTAL) {
        char* ws = (char*)d_ws;
        build_w<<<dim3(LAYERS*8), 256, 0, stream>>>(kr, ki, ws);
        // binary cascade, in place: item j of pass p at slot j*2^p
        compose<<<dim3(12*4), 512, 0, stream>>>(ws,  1, 12);  // 25 -> 13
        compose<<<dim3( 6*4), 512, 0, stream>>>(ws,  2,  6);  // 13 ->  7
        compose<<<dim3( 3*4), 512, 0, stream>>>(ws,  4,  3);  //  7 ->  4
        compose<<<dim3( 2*4), 512, 0, stream>>>(ws,  8,  2);  //  4 ->  2
        compose<<<dim3( 1*4), 512, 0, stream>>>(ws, 16,  1);  //  2 ->  1
        hqmm2<<<dim3(B_TOTAL/64), 512, 0, stream>>>(sr, si, ws, out, 1);
    } else {
        hqmm_kernel<<<dim3(B_TOTAL/SAMPLES_PER_BLOCK), FB_THREADS, 0, stream>>>(
            sr, si, kr, ki, out);
    }
}